// Round 1
// baseline (4896.764 us; speedup 1.0000x reference)
//
#include <hip/hip_runtime.h>
#include <hip/hip_bf16.h>

static constexpr int NN = 1000000;   // nodes
static constexpr int NE = 5000000;   // edges
static constexpr int NG = 4096;      // graphs

// transform(x) == tanh(x) for finite x (nan_to_num / clip are no-ops on tanh output)
__device__ __forceinline__ float fast_tanh(float x) {
    x = fminf(fmaxf(x, -10.0f), 10.0f);      // keep exp finite; tanh(10)==1.0f in f32
    float e = __expf(2.0f * x);
    return (e - 1.0f) / (e + 1.0f);
}

// One thread per edge: recompute h1[col] on the fly (layer-1 MLP + tanh),
// scatter-add into agg[row][:], bump deg[row].
__global__ __launch_bounds__(256) void edge_scatter_k(
    const float* __restrict__ x,
    const int* __restrict__ row,
    const int* __restrict__ col,
    const float* __restrict__ w1,   // [3,16]
    const float* __restrict__ b1,   // [16]
    float* __restrict__ agg,        // [NN,16]
    float* __restrict__ deg)        // [NN]
{
    int e = blockIdx.x * 256 + threadIdx.x;
    if (e >= NE) return;
    int r = row[e];
    int c = col[e];
    float x0 = x[3 * c + 0], x1 = x[3 * c + 1], x2 = x[3 * c + 2];
    float* ar = agg + (size_t)r * 16;
#pragma unroll
    for (int j = 0; j < 16; ++j) {
        float v = fmaf(x2, w1[32 + j], fmaf(x1, w1[16 + j], fmaf(x0, w1[j], b1[j])));
        unsafeAtomicAdd(&ar[j], fast_tanh(v));
    }
    unsafeAtomicAdd(&deg[r], 1.0f);
}

// One thread per node: normalize agg by deg, layer-2 MLP + tanh, then pool
// into per-graph sum/max/count. batch is sorted -> most waves are uniform in
// graph id; pre-reduce those with shuffles and emit 1 atomic set per wave.
__global__ __launch_bounds__(256) void node_pool_k(
    const float* __restrict__ agg,
    const float* __restrict__ deg,
    const int* __restrict__ batch,
    const float* __restrict__ w2,   // [16,16]
    const float* __restrict__ b2,   // [16]
    float* __restrict__ h_sum,      // [NG,16]
    unsigned int* __restrict__ h_max, // [NG,16], monotone-encoded f32
    int* __restrict__ cnt)          // [NG]
{
    int i = blockIdx.x * 256 + threadIdx.x;
    if (i >= NN) return;            // NN % 64 == 0 -> waves fully active or fully exited

    float inv = 1.0f / fmaxf(deg[i], 1.0f);
    const float4* ap = (const float4*)(agg + (size_t)i * 16);
    float4 A0 = ap[0], A1 = ap[1], A2 = ap[2], A3 = ap[3];
    float a[16] = {A0.x, A0.y, A0.z, A0.w, A1.x, A1.y, A1.z, A1.w,
                   A2.x, A2.y, A2.z, A2.w, A3.x, A3.y, A3.z, A3.w};
#pragma unroll
    for (int k = 0; k < 16; ++k) a[k] *= inv;

    float h[16];
#pragma unroll
    for (int j = 0; j < 16; ++j) h[j] = b2[j];
#pragma unroll
    for (int k = 0; k < 16; ++k) {
#pragma unroll
        for (int j = 0; j < 16; ++j) h[j] = fmaf(a[k], w2[16 * k + j], h[j]);
    }
#pragma unroll
    for (int j = 0; j < 16; ++j) h[j] = fast_tanh(h[j]);

    int g = batch[i];
    int lane = threadIdx.x & 63;
    bool uni = __all(g == __shfl(g, 0));
    if (uni) {
#pragma unroll
        for (int j = 0; j < 16; ++j) {
            float s = h[j];
            float m = h[j];
#pragma unroll
            for (int off = 32; off > 0; off >>= 1) {
                s += __shfl_down(s, off);
                m = fmaxf(m, __shfl_down(m, off));
            }
            if (lane == 0) {
                unsafeAtomicAdd(&h_sum[16 * g + j], s);
                atomicMax(&h_max[16 * g + j], __float_as_uint(m + 2.0f));
            }
        }
        if (lane == 0) atomicAdd(&cnt[g], 64);
    } else {
#pragma unroll
        for (int j = 0; j < 16; ++j) {
            unsafeAtomicAdd(&h_sum[16 * g + j], h[j]);
            atomicMax(&h_max[16 * g + j], __float_as_uint(h[j] + 2.0f));
        }
        atomicAdd(&cnt[g], 1);
    }
}

// One thread per graph: mean/max decode, 32->1 head, sigmoid.
__global__ __launch_bounds__(256) void out_k(
    const float* __restrict__ h_sum,
    const unsigned int* __restrict__ h_max,
    const int* __restrict__ cnt,
    const float* __restrict__ w3,   // [32]
    const float* __restrict__ b3,   // [1]
    float* __restrict__ out)        // [NG]
{
    int g = blockIdx.x * 256 + threadIdx.x;
    if (g >= NG) return;
    float invc = 1.0f / fmaxf((float)cnt[g], 1.0f);
    float acc = b3[0];
#pragma unroll
    for (int j = 0; j < 16; ++j) {
        float mean = h_sum[16 * g + j] * invc;
        unsigned int e = h_max[16 * g + j];
        float mx = (e == 0u) ? 0.0f : (__uint_as_float(e) - 2.0f);  // empty graph -> 0
        acc = fmaf(mean, w3[j], fmaf(mx, w3[16 + j], acc));
    }
    out[g] = 1.0f / (1.0f + __expf(-acc));
}

extern "C" void kernel_launch(void* const* d_in, const int* in_sizes, int n_in,
                              void* d_out, int out_size, void* d_ws, size_t ws_size,
                              hipStream_t stream)
{
    const float* x   = (const float*)d_in[0];
    const int*   ei  = (const int*)d_in[1];   // [2, NE]: row = ei, col = ei + NE
    const int*   bat = (const int*)d_in[2];
    const float* w1  = (const float*)d_in[3];
    const float* b1  = (const float*)d_in[4];
    const float* w2  = (const float*)d_in[5];
    const float* b2  = (const float*)d_in[6];
    const float* w3  = (const float*)d_in[7];
    const float* b3  = (const float*)d_in[8];
    float* out = (float*)d_out;

    char* ws = (char*)d_ws;
    size_t off = 0;
    float* agg = (float*)(ws + off);        off += (size_t)NN * 16 * 4;  // 64 MB
    float* deg = (float*)(ws + off);        off += (size_t)NN * 4;       // 4 MB
    float* h_sum = (float*)(ws + off);      off += (size_t)NG * 16 * 4;
    unsigned int* h_max = (unsigned int*)(ws + off); off += (size_t)NG * 16 * 4;
    int* cnt = (int*)(ws + off);            off += (size_t)NG * 4;

    hipMemsetAsync(d_ws, 0, off, stream);   // zero = valid init for all (incl. max sentinel)

    edge_scatter_k<<<(NE + 255) / 256, 256, 0, stream>>>(x, ei, ei + NE, w1, b1, agg, deg);
    node_pool_k<<<(NN + 255) / 256, 256, 0, stream>>>(agg, deg, bat, w2, b2, h_sum, h_max, cnt);
    out_k<<<(NG + 255) / 256, 256, 0, stream>>>(h_sum, h_max, cnt, w3, b3, out);
}

// Round 2
// 1330.048 us; speedup vs baseline: 3.6816x; 3.6816x over previous
//
#include <hip/hip_runtime.h>
#include <hip/hip_bf16.h>

static constexpr int NN = 1000000;   // nodes
static constexpr int NE = 5000000;   // edges
static constexpr int NG = 4096;      // graphs

// transform(x) == tanh(x) for finite x (nan_to_num / clip are no-ops on tanh output)
__device__ __forceinline__ float fast_tanh(float x) {
    x = fminf(fmaxf(x, -10.0f), 10.0f);
    float e = __expf(2.0f * x);
    return (e - 1.0f) / (e + 1.0f);
}

// ---- Step 1: histogram of destination nodes (in-degree) ----
__global__ __launch_bounds__(256) void hist_k(
    const int* __restrict__ row, int* __restrict__ deg)
{
    int e = blockIdx.x * 256 + threadIdx.x;
    if (e >= NE) return;
    atomicAdd(&deg[row[e]], 1);
}

// ---- Step 2: exclusive scan of deg[NN] -> starts[NN], cursor[NN] ----
// 2a: per-block (1024 elements) sums
__global__ __launch_bounds__(256) void scan_block_sums_k(
    const int* __restrict__ deg, int* __restrict__ blockSums)
{
    __shared__ int s[256];
    int b = blockIdx.x, t = threadIdx.x;
    int base = b * 1024 + t * 4;
    int tsum = 0;
#pragma unroll
    for (int k = 0; k < 4; ++k) {
        int idx = base + k;
        tsum += (idx < NN) ? deg[idx] : 0;
    }
    s[t] = tsum;
    __syncthreads();
    for (int off = 128; off > 0; off >>= 1) {
        if (t < off) s[t] += s[t + off];
        __syncthreads();
    }
    if (t == 0) blockSums[b] = s[0];
}

// 2b: single-block exclusive scan of blockSums[nblocks] (nblocks <= 1024)
__global__ __launch_bounds__(1024) void scan_top_k(
    int* __restrict__ blockSums, int nblocks)
{
    __shared__ int s[1024];
    int t = threadIdx.x;
    int v = (t < nblocks) ? blockSums[t] : 0;
    s[t] = v;
    __syncthreads();
    for (int off = 1; off < 1024; off <<= 1) {
        int u = (t >= off) ? s[t - off] : 0;
        __syncthreads();
        s[t] += u;
        __syncthreads();
    }
    if (t < nblocks) blockSums[t] = s[t] - v;   // exclusive
}

// 2c: per-block local exclusive scan + add block offset; write starts & cursor
__global__ __launch_bounds__(256) void scan_final_k(
    const int* __restrict__ deg, const int* __restrict__ blockOffsets,
    int* __restrict__ starts, int* __restrict__ cursor)
{
    __shared__ int s[256];
    int b = blockIdx.x, t = threadIdx.x;
    int base = b * 1024 + t * 4;
    int d[4];
    int tsum = 0;
#pragma unroll
    for (int k = 0; k < 4; ++k) {
        int idx = base + k;
        d[k] = (idx < NN) ? deg[idx] : 0;
        tsum += d[k];
    }
    s[t] = tsum;
    __syncthreads();
    for (int off = 1; off < 256; off <<= 1) {
        int u = (t >= off) ? s[t - off] : 0;
        __syncthreads();
        s[t] += u;
        __syncthreads();
    }
    int run = blockOffsets[b] + s[t] - tsum;    // exclusive across threads
#pragma unroll
    for (int k = 0; k < 4; ++k) {
        int idx = base + k;
        if (idx < NN) { starts[idx] = run; cursor[idx] = run; }
        run += d[k];
    }
}

// ---- Step 3: scatter edges into CSR order ----
__global__ __launch_bounds__(256) void scatter_k(
    const int* __restrict__ row, const int* __restrict__ col,
    int* __restrict__ cursor, int* __restrict__ sorted_col)
{
    int e = blockIdx.x * 256 + threadIdx.x;
    if (e >= NE) return;
    int pos = atomicAdd(&cursor[row[e]], 1);
    sorted_col[pos] = col[e];
}

// ---- Step 4: fused pull-aggregation + MLP2 + pooling ----
__global__ __launch_bounds__(256) void node_k(
    const float* __restrict__ x,
    const int* __restrict__ starts,
    const int* __restrict__ deg,
    const int* __restrict__ sorted_col,
    const int* __restrict__ batch,
    const float* __restrict__ w1,   // [3,16]
    const float* __restrict__ b1,   // [16]
    const float* __restrict__ w2,   // [16,16]
    const float* __restrict__ b2,   // [16]
    float* __restrict__ h_sum,      // [NG,16]
    unsigned int* __restrict__ h_max, // [NG,16] monotone-encoded
    int* __restrict__ cnt)          // [NG]
{
    int i = blockIdx.x * 256 + threadIdx.x;
    if (i >= NN) return;            // NN % 64 == 0 -> whole waves exit

    int st = starts[i];
    int dg = deg[i];
    float acc[16];
#pragma unroll
    for (int j = 0; j < 16; ++j) acc[j] = 0.0f;

    for (int e = 0; e < dg; ++e) {
        int c = sorted_col[st + e];
        float x0 = x[3 * c + 0], x1 = x[3 * c + 1], x2 = x[3 * c + 2];
#pragma unroll
        for (int j = 0; j < 16; ++j) {
            float v = fmaf(x2, w1[32 + j], fmaf(x1, w1[16 + j], fmaf(x0, w1[j], b1[j])));
            acc[j] += fast_tanh(v);
        }
    }

    float inv = 1.0f / fmaxf((float)dg, 1.0f);
    float h[16];
#pragma unroll
    for (int j = 0; j < 16; ++j) h[j] = b2[j];
#pragma unroll
    for (int k = 0; k < 16; ++k) {
        float a = acc[k] * inv;
#pragma unroll
        for (int j = 0; j < 16; ++j) h[j] = fmaf(a, w2[16 * k + j], h[j]);
    }
#pragma unroll
    for (int j = 0; j < 16; ++j) h[j] = fast_tanh(h[j]);

    int g = batch[i];
    int lane = threadIdx.x & 63;
    bool uni = __all(g == __shfl(g, 0));
    if (uni) {
#pragma unroll
        for (int j = 0; j < 16; ++j) {
            float s = h[j];
            float m = h[j];
#pragma unroll
            for (int off = 32; off > 0; off >>= 1) {
                s += __shfl_down(s, off);
                m = fmaxf(m, __shfl_down(m, off));
            }
            if (lane == 0) {
                unsafeAtomicAdd(&h_sum[16 * g + j], s);
                atomicMax(&h_max[16 * g + j], __float_as_uint(m + 2.0f));
            }
        }
        if (lane == 0) atomicAdd(&cnt[g], 64);
    } else {
#pragma unroll
        for (int j = 0; j < 16; ++j) {
            unsafeAtomicAdd(&h_sum[16 * g + j], h[j]);
            atomicMax(&h_max[16 * g + j], __float_as_uint(h[j] + 2.0f));
        }
        atomicAdd(&cnt[g], 1);
    }
}

// ---- Step 5: head ----
__global__ __launch_bounds__(256) void out_k(
    const float* __restrict__ h_sum,
    const unsigned int* __restrict__ h_max,
    const int* __restrict__ cnt,
    const float* __restrict__ w3,   // [32]
    const float* __restrict__ b3,   // [1]
    float* __restrict__ out)        // [NG]
{
    int g = blockIdx.x * 256 + threadIdx.x;
    if (g >= NG) return;
    float invc = 1.0f / fmaxf((float)cnt[g], 1.0f);
    float acc = b3[0];
#pragma unroll
    for (int j = 0; j < 16; ++j) {
        float mean = h_sum[16 * g + j] * invc;
        unsigned int e = h_max[16 * g + j];
        float mx = (e == 0u) ? 0.0f : (__uint_as_float(e) - 2.0f);
        acc = fmaf(mean, w3[j], fmaf(mx, w3[16 + j], acc));
    }
    out[g] = 1.0f / (1.0f + __expf(-acc));
}

extern "C" void kernel_launch(void* const* d_in, const int* in_sizes, int n_in,
                              void* d_out, int out_size, void* d_ws, size_t ws_size,
                              hipStream_t stream)
{
    const float* x   = (const float*)d_in[0];
    const int*   ei  = (const int*)d_in[1];   // row = ei, col = ei + NE
    const int*   bat = (const int*)d_in[2];
    const float* w1  = (const float*)d_in[3];
    const float* b1  = (const float*)d_in[4];
    const float* w2  = (const float*)d_in[5];
    const float* b2  = (const float*)d_in[6];
    const float* w3  = (const float*)d_in[7];
    const float* b3  = (const float*)d_in[8];
    float* out = (float*)d_out;

    constexpr int SCAN_BLOCKS = (NN + 1023) / 1024;   // 977

    char* ws = (char*)d_ws;
    size_t off = 0;
    // --- zeroed region (one small memset) ---
    int* deg      = (int*)(ws + off);          off += (size_t)NN * 4;       // 4 MB
    float* h_sum  = (float*)(ws + off);        off += (size_t)NG * 16 * 4;
    unsigned int* h_max = (unsigned int*)(ws + off); off += (size_t)NG * 16 * 4;
    int* cnt      = (int*)(ws + off);          off += (size_t)NG * 4;
    size_t zero_bytes = off;
    // --- non-zeroed scratch ---
    int* starts   = (int*)(ws + off);          off += (size_t)NN * 4;
    int* cursor   = (int*)(ws + off);          off += (size_t)NN * 4;
    int* blockSums= (int*)(ws + off);          off += (size_t)1024 * 4;
    int* sorted_col=(int*)(ws + off);          off += (size_t)NE * 4;

    hipMemsetAsync(d_ws, 0, zero_bytes, stream);

    hist_k<<<(NE + 255) / 256, 256, 0, stream>>>(ei, deg);
    scan_block_sums_k<<<SCAN_BLOCKS, 256, 0, stream>>>(deg, blockSums);
    scan_top_k<<<1, 1024, 0, stream>>>(blockSums, SCAN_BLOCKS);
    scan_final_k<<<SCAN_BLOCKS, 256, 0, stream>>>(deg, blockSums, starts, cursor);
    scatter_k<<<(NE + 255) / 256, 256, 0, stream>>>(ei, ei + NE, cursor, sorted_col);
    node_k<<<(NN + 255) / 256, 256, 0, stream>>>(x, starts, deg, sorted_col, bat,
                                                 w1, b1, w2, b2, h_sum, h_max, cnt);
    out_k<<<(NG + 255) / 256, 256, 0, stream>>>(h_sum, h_max, cnt, w3, b3, out);
}

// Round 3
// 1102.465 us; speedup vs baseline: 4.4416x; 1.2064x over previous
//
#include <hip/hip_runtime.h>
#include <hip/hip_bf16.h>

static constexpr int NN = 1000000;   // nodes
static constexpr int NE = 5000000;   // edges
static constexpr int NG = 4096;      // graphs

// transform(x) == tanh(x) for finite x (nan_to_num / clip are no-ops on tanh output)
__device__ __forceinline__ float fast_tanh(float x) {
    x = fminf(fmaxf(x, -10.0f), 10.0f);
    float e = __expf(2.0f * x);
    return (e - 1.0f) / (e + 1.0f);
}

// ---- Step 1: histogram of destination nodes (in-degree) ----
__global__ __launch_bounds__(256) void hist_k(
    const int* __restrict__ row, int* __restrict__ deg)
{
    int e = blockIdx.x * 256 + threadIdx.x;
    if (e >= NE) return;
    atomicAdd(&deg[row[e]], 1);
}

// ---- Step 2: exclusive scan of deg[NN] -> cursor[NN] ----
__global__ __launch_bounds__(256) void scan_block_sums_k(
    const int* __restrict__ deg, int* __restrict__ blockSums)
{
    __shared__ int s[256];
    int b = blockIdx.x, t = threadIdx.x;
    int base = b * 1024 + t * 4;
    int tsum = 0;
#pragma unroll
    for (int k = 0; k < 4; ++k) {
        int idx = base + k;
        tsum += (idx < NN) ? deg[idx] : 0;
    }
    s[t] = tsum;
    __syncthreads();
    for (int off = 128; off > 0; off >>= 1) {
        if (t < off) s[t] += s[t + off];
        __syncthreads();
    }
    if (t == 0) blockSums[b] = s[0];
}

__global__ __launch_bounds__(1024) void scan_top_k(
    int* __restrict__ blockSums, int nblocks)
{
    __shared__ int s[1024];
    int t = threadIdx.x;
    int v = (t < nblocks) ? blockSums[t] : 0;
    s[t] = v;
    __syncthreads();
    for (int off = 1; off < 1024; off <<= 1) {
        int u = (t >= off) ? s[t - off] : 0;
        __syncthreads();
        s[t] += u;
        __syncthreads();
    }
    if (t < nblocks) blockSums[t] = s[t] - v;   // exclusive
}

__global__ __launch_bounds__(256) void scan_final_k(
    const int* __restrict__ deg, const int* __restrict__ blockOffsets,
    int* __restrict__ cursor)
{
    __shared__ int s[256];
    int b = blockIdx.x, t = threadIdx.x;
    int base = b * 1024 + t * 4;
    int d[4];
    int tsum = 0;
#pragma unroll
    for (int k = 0; k < 4; ++k) {
        int idx = base + k;
        d[k] = (idx < NN) ? deg[idx] : 0;
        tsum += d[k];
    }
    s[t] = tsum;
    __syncthreads();
    for (int off = 1; off < 256; off <<= 1) {
        int u = (t >= off) ? s[t - off] : 0;
        __syncthreads();
        s[t] += u;
        __syncthreads();
    }
    int run = blockOffsets[b] + s[t] - tsum;    // exclusive across threads
#pragma unroll
    for (int k = 0; k < 4; ++k) {
        int idx = base + k;
        if (idx < NN) cursor[idx] = run;
        run += d[k];
    }
}

// ---- Step 3: scatter the SOURCE FEATURES into CSR order ----
// Pays the x-gather latency here (overlapped with the returning atomic), so
// the aggregation kernel downstream is a pure streaming read.
__global__ __launch_bounds__(256) void scatter_x_k(
    const int* __restrict__ row, const int* __restrict__ col,
    const float* __restrict__ x,
    int* __restrict__ cursor, float* __restrict__ sorted_x)
{
    int e = blockIdx.x * 256 + threadIdx.x;
    if (e >= NE) return;
    int r = row[e];
    int c = col[e];
    float x0 = x[3 * c + 0], x1 = x[3 * c + 1], x2 = x[3 * c + 2];
    int pos = atomicAdd(&cursor[r], 1);
    sorted_x[3 * pos + 0] = x0;
    sorted_x[3 * pos + 1] = x1;
    sorted_x[3 * pos + 2] = x2;
}

// ---- Step 4: fused streaming aggregation + MLP2 + pooling ----
// After scatter, cursor[i] == start(i) + deg[i], so start = cursor - deg.
__global__ __launch_bounds__(256) void agg_pool_k(
    const float* __restrict__ sorted_x,
    const int* __restrict__ cursor,
    const int* __restrict__ deg,
    const int* __restrict__ batch,
    const float* __restrict__ w1,   // [3,16]
    const float* __restrict__ b1,   // [16]
    const float* __restrict__ w2,   // [16,16]
    const float* __restrict__ b2,   // [16]
    float* __restrict__ h_sum,      // [NG,16]
    unsigned int* __restrict__ h_max, // [NG,16] monotone-encoded
    int* __restrict__ cnt)          // [NG]
{
    int i = blockIdx.x * 256 + threadIdx.x;
    if (i >= NN) return;            // NN % 64 == 0 -> whole waves exit

    int dg = deg[i];
    int st = cursor[i] - dg;
    float acc[16];
#pragma unroll
    for (int j = 0; j < 16; ++j) acc[j] = 0.0f;

    for (int e = 0; e < dg; ++e) {
        const float* sx = sorted_x + 3 * (size_t)(st + e);
        float x0 = sx[0], x1 = sx[1], x2 = sx[2];
#pragma unroll
        for (int j = 0; j < 16; ++j) {
            float v = fmaf(x2, w1[32 + j], fmaf(x1, w1[16 + j], fmaf(x0, w1[j], b1[j])));
            acc[j] += fast_tanh(v);
        }
    }

    float inv = 1.0f / fmaxf((float)dg, 1.0f);
    float h[16];
#pragma unroll
    for (int j = 0; j < 16; ++j) h[j] = b2[j];
#pragma unroll
    for (int k = 0; k < 16; ++k) {
        float a = acc[k] * inv;
#pragma unroll
        for (int j = 0; j < 16; ++j) h[j] = fmaf(a, w2[16 * k + j], h[j]);
    }
#pragma unroll
    for (int j = 0; j < 16; ++j) h[j] = fast_tanh(h[j]);

    int g = batch[i];
    int lane = threadIdx.x & 63;
    bool uni = __all(g == __shfl(g, 0));
    if (uni) {
#pragma unroll
        for (int j = 0; j < 16; ++j) {
            float s = h[j];
            float m = h[j];
#pragma unroll
            for (int off = 32; off > 0; off >>= 1) {
                s += __shfl_down(s, off);
                m = fmaxf(m, __shfl_down(m, off));
            }
            if (lane == 0) {
                unsafeAtomicAdd(&h_sum[16 * g + j], s);
                atomicMax(&h_max[16 * g + j], __float_as_uint(m + 2.0f));
            }
        }
        if (lane == 0) atomicAdd(&cnt[g], 64);
    } else {
#pragma unroll
        for (int j = 0; j < 16; ++j) {
            unsafeAtomicAdd(&h_sum[16 * g + j], h[j]);
            atomicMax(&h_max[16 * g + j], __float_as_uint(h[j] + 2.0f));
        }
        atomicAdd(&cnt[g], 1);
    }
}

// ---- Step 5: head ----
__global__ __launch_bounds__(256) void out_k(
    const float* __restrict__ h_sum,
    const unsigned int* __restrict__ h_max,
    const int* __restrict__ cnt,
    const float* __restrict__ w3,   // [32]
    const float* __restrict__ b3,   // [1]
    float* __restrict__ out)        // [NG]
{
    int g = blockIdx.x * 256 + threadIdx.x;
    if (g >= NG) return;
    float invc = 1.0f / fmaxf((float)cnt[g], 1.0f);
    float acc = b3[0];
#pragma unroll
    for (int j = 0; j < 16; ++j) {
        float mean = h_sum[16 * g + j] * invc;
        unsigned int e = h_max[16 * g + j];
        float mx = (e == 0u) ? 0.0f : (__uint_as_float(e) - 2.0f);
        acc = fmaf(mean, w3[j], fmaf(mx, w3[16 + j], acc));
    }
    out[g] = 1.0f / (1.0f + __expf(-acc));
}

extern "C" void kernel_launch(void* const* d_in, const int* in_sizes, int n_in,
                              void* d_out, int out_size, void* d_ws, size_t ws_size,
                              hipStream_t stream)
{
    const float* x   = (const float*)d_in[0];
    const int*   ei  = (const int*)d_in[1];   // row = ei, col = ei + NE
    const int*   bat = (const int*)d_in[2];
    const float* w1  = (const float*)d_in[3];
    const float* b1  = (const float*)d_in[4];
    const float* w2  = (const float*)d_in[5];
    const float* b2  = (const float*)d_in[6];
    const float* w3  = (const float*)d_in[7];
    const float* b3  = (const float*)d_in[8];
    float* out = (float*)d_out;

    constexpr int SCAN_BLOCKS = (NN + 1023) / 1024;   // 977

    char* ws = (char*)d_ws;
    size_t off = 0;
    // --- zeroed region (one small memset, 4.54 MB) ---
    int* deg      = (int*)(ws + off);          off += (size_t)NN * 4;
    float* h_sum  = (float*)(ws + off);        off += (size_t)NG * 16 * 4;
    unsigned int* h_max = (unsigned int*)(ws + off); off += (size_t)NG * 16 * 4;
    int* cnt      = (int*)(ws + off);          off += (size_t)NG * 4;
    size_t zero_bytes = off;
    // --- non-zeroed scratch ---
    int* cursor   = (int*)(ws + off);          off += (size_t)NN * 4;
    float* sorted_x = (float*)(ws + off);      off += (size_t)NE * 3 * 4;  // 60 MB
    // blockSums aliases the head of sorted_x: last read (scan_final_k) happens
    // before scatter_x_k clobbers it. Keeps total ws at 68.54 MB (round-1-proven).
    int* blockSums = (int*)sorted_x;

    hipMemsetAsync(d_ws, 0, zero_bytes, stream);

    hist_k<<<(NE + 255) / 256, 256, 0, stream>>>(ei, deg);
    scan_block_sums_k<<<SCAN_BLOCKS, 256, 0, stream>>>(deg, blockSums);
    scan_top_k<<<1, 1024, 0, stream>>>(blockSums, SCAN_BLOCKS);
    scan_final_k<<<SCAN_BLOCKS, 256, 0, stream>>>(deg, blockSums, cursor);
    scatter_x_k<<<(NE + 255) / 256, 256, 0, stream>>>(ei, ei + NE, x, cursor, sorted_x);
    agg_pool_k<<<(NN + 255) / 256, 256, 0, stream>>>(sorted_x, cursor, deg, bat,
                                                     w1, b1, w2, b2, h_sum, h_max, cnt);
    out_k<<<(NG + 255) / 256, 256, 0, stream>>>(h_sum, h_max, cnt, w3, b3, out);
}

// Round 4
// 588.496 us; speedup vs baseline: 8.3208x; 1.8734x over previous
//
#include <hip/hip_runtime.h>
#include <hip/hip_bf16.h>

static constexpr int NN = 1000000;   // nodes
static constexpr int NE = 5000000;   // edges
static constexpr int NG = 4096;      // graphs

// transform(x) == tanh(x) for finite x (nan_to_num / clip are no-ops on tanh output)
__device__ __forceinline__ float fast_tanh(float x) {
    x = fminf(fmaxf(x, -10.0f), 10.0f);
    float e = __expf(2.0f * x);
    return (e - 1.0f) / (e + 1.0f);
}

// ---- Step 1: histogram of destination nodes (in-degree) ----
__global__ __launch_bounds__(256) void hist_k(
    const int* __restrict__ row, int* __restrict__ deg)
{
    int e = blockIdx.x * 256 + threadIdx.x;
    if (e >= NE) return;
    atomicAdd(&deg[row[e]], 1);
}

// ---- Step 2: exclusive scan of deg[NN] -> cursor[NN] ----
__global__ __launch_bounds__(256) void scan_block_sums_k(
    const int* __restrict__ deg, int* __restrict__ blockSums)
{
    __shared__ int s[256];
    int b = blockIdx.x, t = threadIdx.x;
    int base = b * 1024 + t * 4;
    int tsum = 0;
#pragma unroll
    for (int k = 0; k < 4; ++k) {
        int idx = base + k;
        tsum += (idx < NN) ? deg[idx] : 0;
    }
    s[t] = tsum;
    __syncthreads();
    for (int off = 128; off > 0; off >>= 1) {
        if (t < off) s[t] += s[t + off];
        __syncthreads();
    }
    if (t == 0) blockSums[b] = s[0];
}

__global__ __launch_bounds__(1024) void scan_top_k(
    int* __restrict__ blockSums, int nblocks)
{
    __shared__ int s[1024];
    int t = threadIdx.x;
    int v = (t < nblocks) ? blockSums[t] : 0;
    s[t] = v;
    __syncthreads();
    for (int off = 1; off < 1024; off <<= 1) {
        int u = (t >= off) ? s[t - off] : 0;
        __syncthreads();
        s[t] += u;
        __syncthreads();
    }
    if (t < nblocks) blockSums[t] = s[t] - v;   // exclusive
}

__global__ __launch_bounds__(256) void scan_final_k(
    const int* __restrict__ deg, const int* __restrict__ blockOffsets,
    int* __restrict__ cursor)
{
    __shared__ int s[256];
    int b = blockIdx.x, t = threadIdx.x;
    int base = b * 1024 + t * 4;
    int d[4];
    int tsum = 0;
#pragma unroll
    for (int k = 0; k < 4; ++k) {
        int idx = base + k;
        d[k] = (idx < NN) ? deg[idx] : 0;
        tsum += d[k];
    }
    s[t] = tsum;
    __syncthreads();
    for (int off = 1; off < 256; off <<= 1) {
        int u = (t >= off) ? s[t - off] : 0;
        __syncthreads();
        s[t] += u;
        __syncthreads();
    }
    int run = blockOffsets[b] + s[t] - tsum;    // exclusive across threads
#pragma unroll
    for (int k = 0; k < 4; ++k) {
        int idx = base + k;
        if (idx < NN) cursor[idx] = run;
        run += d[k];
    }
}

// ---- Step 3: scatter the SOURCE FEATURES into CSR order ----
// Issue the returning atomic FIRST so its latency overlaps the x-gather.
__global__ __launch_bounds__(256) void scatter_x_k(
    const int* __restrict__ row, const int* __restrict__ col,
    const float* __restrict__ x,
    int* __restrict__ cursor, float* __restrict__ sorted_x)
{
    int e = blockIdx.x * 256 + threadIdx.x;
    if (e >= NE) return;
    int r = row[e];
    int c = col[e];
    int pos = atomicAdd(&cursor[r], 1);
    float x0 = x[3 * c + 0], x1 = x[3 * c + 1], x2 = x[3 * c + 2];
    sorted_x[3 * pos + 0] = x0;
    sorted_x[3 * pos + 1] = x1;
    sorted_x[3 * pos + 2] = x2;
}

// ---- Step 4: fused streaming aggregation + MLP2 + segmented-scan pooling ----
// After scatter, cursor[i] == start(i) + deg[i], so start = cursor - deg.
__global__ __launch_bounds__(256) void agg_pool_k(
    const float* __restrict__ sorted_x,
    const int* __restrict__ cursor,
    const int* __restrict__ deg,
    const int* __restrict__ batch,
    const float* __restrict__ w1,   // [3,16]
    const float* __restrict__ b1,   // [16]
    const float* __restrict__ w2,   // [16,16]
    const float* __restrict__ b2,   // [16]
    float* __restrict__ h_sum,      // [NG,16]
    unsigned int* __restrict__ h_max, // [NG,16] monotone-encoded
    int* __restrict__ cnt)          // [NG]
{
    int i = blockIdx.x * 256 + threadIdx.x;
    if (i >= NN) return;            // NN % 64 == 0 -> whole waves exit

    int dg = deg[i];
    int st = cursor[i] - dg;
    float acc[16];
#pragma unroll
    for (int j = 0; j < 16; ++j) acc[j] = 0.0f;

    for (int e = 0; e < dg; ++e) {
        const float* sx = sorted_x + 3 * (size_t)(st + e);
        float x0 = sx[0], x1 = sx[1], x2 = sx[2];
#pragma unroll
        for (int j = 0; j < 16; ++j) {
            float v = fmaf(x2, w1[32 + j], fmaf(x1, w1[16 + j], fmaf(x0, w1[j], b1[j])));
            acc[j] += fast_tanh(v);
        }
    }

    float inv = 1.0f / fmaxf((float)dg, 1.0f);
    float s[16];   // will hold h, then segmented-scanned sums
#pragma unroll
    for (int j = 0; j < 16; ++j) s[j] = b2[j];
#pragma unroll
    for (int k = 0; k < 16; ++k) {
        float a = acc[k] * inv;
#pragma unroll
        for (int j = 0; j < 16; ++j) s[j] = fmaf(a, w2[16 * k + j], s[j]);
    }
    float m[16];
#pragma unroll
    for (int j = 0; j < 16; ++j) { s[j] = fast_tanh(s[j]); m[j] = s[j]; }

    // ---- segmented wave reduction over sorted batch ids ----
    int g = batch[i];
    int lane = threadIdx.x & 63;
    int gp = __shfl_up(g, 1);
    int head = (lane == 0) || (g != gp);
    unsigned long long hm = __ballot(head != 0);

    int f = head;
#pragma unroll
    for (int off = 1; off < 64; off <<= 1) {
        int fu = __shfl_up(f, off);
        bool take = (lane >= off) && (f == 0);
#pragma unroll
        for (int j = 0; j < 16; ++j) {
            float su = __shfl_up(s[j], off);
            float mu = __shfl_up(m[j], off);
            if (take) { s[j] += su; m[j] = fmaxf(m[j], mu); }
        }
        if (lane >= off) f |= fu;
    }

    int hnext = __shfl_down(head, 1);
    bool is_last = (lane == 63) || (hnext != 0);
    if (is_last) {
        unsigned long long below = hm & (~0ULL >> (63 - lane));  // head bits <= lane
        int start = 63 - __clzll(below);
        int seglen = lane - start + 1;
#pragma unroll
        for (int j = 0; j < 16; ++j) {
            unsafeAtomicAdd(&h_sum[16 * g + j], s[j]);
            atomicMax(&h_max[16 * g + j], __float_as_uint(m[j] + 2.0f));
        }
        atomicAdd(&cnt[g], seglen);
    }
}

// ---- Step 5: head ----
__global__ __launch_bounds__(256) void out_k(
    const float* __restrict__ h_sum,
    const unsigned int* __restrict__ h_max,
    const int* __restrict__ cnt,
    const float* __restrict__ w3,   // [32]
    const float* __restrict__ b3,   // [1]
    float* __restrict__ out)        // [NG]
{
    int g = blockIdx.x * 256 + threadIdx.x;
    if (g >= NG) return;
    float invc = 1.0f / fmaxf((float)cnt[g], 1.0f);
    float acc = b3[0];
#pragma unroll
    for (int j = 0; j < 16; ++j) {
        float mean = h_sum[16 * g + j] * invc;
        unsigned int e = h_max[16 * g + j];
        float mx = (e == 0u) ? 0.0f : (__uint_as_float(e) - 2.0f);
        acc = fmaf(mean, w3[j], fmaf(mx, w3[16 + j], acc));
    }
    out[g] = 1.0f / (1.0f + __expf(-acc));
}

extern "C" void kernel_launch(void* const* d_in, const int* in_sizes, int n_in,
                              void* d_out, int out_size, void* d_ws, size_t ws_size,
                              hipStream_t stream)
{
    const float* x   = (const float*)d_in[0];
    const int*   ei  = (const int*)d_in[1];   // row = ei, col = ei + NE
    const int*   bat = (const int*)d_in[2];
    const float* w1  = (const float*)d_in[3];
    const float* b1  = (const float*)d_in[4];
    const float* w2  = (const float*)d_in[5];
    const float* b2  = (const float*)d_in[6];
    const float* w3  = (const float*)d_in[7];
    const float* b3  = (const float*)d_in[8];
    float* out = (float*)d_out;

    constexpr int SCAN_BLOCKS = (NN + 1023) / 1024;   // 977

    char* ws = (char*)d_ws;
    size_t off = 0;
    // --- zeroed region (one small memset, 4.54 MB) ---
    int* deg      = (int*)(ws + off);          off += (size_t)NN * 4;
    float* h_sum  = (float*)(ws + off);        off += (size_t)NG * 16 * 4;
    unsigned int* h_max = (unsigned int*)(ws + off); off += (size_t)NG * 16 * 4;
    int* cnt      = (int*)(ws + off);          off += (size_t)NG * 4;
    size_t zero_bytes = off;
    // --- non-zeroed scratch ---
    int* cursor   = (int*)(ws + off);          off += (size_t)NN * 4;
    float* sorted_x = (float*)(ws + off);      off += (size_t)NE * 3 * 4;  // 60 MB
    // blockSums aliases the head of sorted_x: last read (scan_final_k) happens
    // before scatter_x_k clobbers it. Keeps total ws at 68.54 MB.
    int* blockSums = (int*)sorted_x;

    hipMemsetAsync(d_ws, 0, zero_bytes, stream);

    hist_k<<<(NE + 255) / 256, 256, 0, stream>>>(ei, deg);
    scan_block_sums_k<<<SCAN_BLOCKS, 256, 0, stream>>>(deg, blockSums);
    scan_top_k<<<1, 1024, 0, stream>>>(blockSums, SCAN_BLOCKS);
    scan_final_k<<<SCAN_BLOCKS, 256, 0, stream>>>(deg, blockSums, cursor);
    scatter_x_k<<<(NE + 255) / 256, 256, 0, stream>>>(ei, ei + NE, x, cursor, sorted_x);
    agg_pool_k<<<(NN + 255) / 256, 256, 0, stream>>>(sorted_x, cursor, deg, bat,
                                                     w1, b1, w2, b2, h_sum, h_max, cnt);
    out_k<<<(NG + 255) / 256, 256, 0, stream>>>(h_sum, h_max, cnt, w3, b3, out);
}